// Round 3
// baseline (81.878 us; speedup 1.0000x reference)
//
#include <hip/hip_runtime.h>
#include <hip/hip_bf16.h>

// Single-head causal attention, B=4096, T=64, C=128, H=64.
// One block / batch, 4 waves, wave w owns query rows [16w,16w+16).
// All matmuls bf16 MFMA 16x16x32. QKV and QK^T are operand-swapped so that
// q/k/P tiles land row-packed (b64 LDS writes) and softmax is lane-local.

typedef __bf16 bf16_t;
typedef __bf16 bf16x8 __attribute__((ext_vector_type(8)));
typedef __bf16 bf16x4 __attribute__((ext_vector_type(4)));
typedef float  f32x4  __attribute__((ext_vector_type(4)));

#define K_OFF   0        // K [s][h]  64x64 bf16, rowstride 128 B, swizzled
#define VT_OFF  8192     // VT [h][s] 64x64 bf16
#define QS_OFF  16384    // per-wave scratch (q then P): w*2048, 16x64 bf16
#define LDS_BYTES 24576

__device__ __forceinline__ int swz(int off, int row) { return off ^ ((row & 7) << 4); }

__device__ __forceinline__ bf16x8 cvt8(const float* p) {
    float4 a = *reinterpret_cast<const float4*>(p);
    float4 b = *reinterpret_cast<const float4*>(p + 4);
    bf16x8 r;
    r[0] = (bf16_t)a.x; r[1] = (bf16_t)a.y; r[2] = (bf16_t)a.z; r[3] = (bf16_t)a.w;
    r[4] = (bf16_t)b.x; r[5] = (bf16_t)b.y; r[6] = (bf16_t)b.z; r[7] = (bf16_t)b.w;
    return r;
}

// W bf16 layout in ws: w2[(ks*192 + h)*32 + c], ks-major so the per-ks
// working set (12 KB) is L1-resident while all waves sweep it.
__global__ void wcvt_kernel(const float* __restrict__ Wq, const float* __restrict__ Wk,
                            const float* __restrict__ Wv, bf16_t* __restrict__ w2)
{
    int i   = blockIdx.x * 256 + threadIdx.x;   // 6144 threads, 4 elems each
    int ks  = i / 1536;
    int rem = i - ks * 1536;
    int h   = rem >> 3;
    int c4  = (rem & 7) * 4;
    const float* wr = (h < 64) ? Wq + h * 128 : (h < 128) ? Wk + (h - 64) * 128
                                                          : Wv + (h - 128) * 128;
    float4 v = *reinterpret_cast<const float4*>(wr + ks * 32 + c4);
    bf16x4 pk;
    pk[0] = (bf16_t)v.x; pk[1] = (bf16_t)v.y; pk[2] = (bf16_t)v.z; pk[3] = (bf16_t)v.w;
    *reinterpret_cast<bf16x4*>(w2 + (ks * 192 + h) * 32 + c4) = pk;
}

template<bool USE_WS>
__global__ __launch_bounds__(256, 5)
void head_attn_kernel(const float* __restrict__ x,
                      const float* __restrict__ Wq,
                      const float* __restrict__ Wk,
                      const float* __restrict__ Wv,
                      const bf16_t* __restrict__ w2,
                      float* __restrict__ out)
{
    __shared__ __align__(16) char smem[LDS_BYTES];
    const int b    = blockIdx.x;
    const int tid  = threadIdx.x;
    const int w    = tid >> 6;
    const int lane = tid & 63;
    const int l15  = lane & 15;
    const int lg   = lane >> 4;
    const int t    = w * 16 + l15;      // this lane's owned query/time row

    // ------------- QKV (swapped): D[h][t] = W[h][:] . x[t][:] -------------
    // acc[j]: h-tile j (q: 0..3, k: 4..7, v: 8..11); lane = col t, regs = 4 h rows
    f32x4 acc[12];
    #pragma unroll
    for (int j = 0; j < 12; ++j) acc[j] = (f32x4){0.f, 0.f, 0.f, 0.f};

    const float* xrow = x + (size_t)b * 8192 + t * 128;
    #pragma unroll
    for (int ks = 0; ks < 4; ++ks) {
        bf16x8 xf = cvt8(xrow + ks * 32 + lg * 8);       // B-frag: lane's own x row
        #pragma unroll
        for (int j = 0; j < 12; ++j) {
            bf16x8 wf;
            if constexpr (USE_WS) {
                wf = *reinterpret_cast<const bf16x8*>(w2 + (ks * 192 + j * 16 + l15) * 32 + lg * 8);
            } else {
                int h = j * 16 + l15;
                const float* wr = (h < 64) ? Wq + h * 128 : (h < 128) ? Wk + (h - 64) * 128
                                                                      : Wv + (h - 128) * 128;
                wf = cvt8(wr + ks * 32 + lg * 8);
            }
            acc[j] = __builtin_amdgcn_mfma_f32_16x16x32_bf16(wf, xf, acc[j], 0, 0, 0);
        }
    }

    // q -> wave-private scratch [t_loc][h] (packed); k -> K[s=t][h] (packed);
    // v -> VT[h][s=t] (scalar scatter, 16 writes)
    char* qscr = smem + QS_OFF + w * 2048;
    #pragma unroll
    for (int j = 0; j < 4; ++j) {
        bf16x4 pk;
        pk[0] = (bf16_t)acc[j][0]; pk[1] = (bf16_t)acc[j][1];
        pk[2] = (bf16_t)acc[j][2]; pk[3] = (bf16_t)acc[j][3];
        *reinterpret_cast<bf16x4*>(qscr + swz(l15 * 128 + (j * 16 + lg * 4) * 2, l15)) = pk;
    }
    #pragma unroll
    for (int j = 4; j < 8; ++j) {
        bf16x4 pk;
        pk[0] = (bf16_t)acc[j][0]; pk[1] = (bf16_t)acc[j][1];
        pk[2] = (bf16_t)acc[j][2]; pk[3] = (bf16_t)acc[j][3];
        *reinterpret_cast<bf16x4*>(smem + swz(K_OFF + t * 128 + ((j - 4) * 16 + lg * 4) * 2, t)) = pk;
    }
    #pragma unroll
    for (int j = 8; j < 12; ++j)
        #pragma unroll
        for (int r = 0; r < 4; ++r) {
            int h = (j - 8) * 16 + lg * 4 + r;
            *reinterpret_cast<bf16_t*>(smem + swz(VT_OFF + h * 128 + t * 2, h)) = (bf16_t)acc[j][r];
        }
    __syncthreads();

    // ------------- S^T = K . q^T : lane = col t (own row), regs = s --------
    f32x4 sacc[4];
    #pragma unroll
    for (int st = 0; st < 4; ++st) sacc[st] = (f32x4){0.f, 0.f, 0.f, 0.f};
    #pragma unroll
    for (int ks = 0; ks < 2; ++ks) {
        int h0 = ks * 32 + lg * 8;
        bf16x8 qf = *reinterpret_cast<const bf16x8*>(qscr + swz(l15 * 128 + h0 * 2, l15));
        #pragma unroll
        for (int st = 0; st < 4; ++st) {
            int s = st * 16 + l15;
            bf16x8 kf = *reinterpret_cast<const bf16x8*>(smem + swz(K_OFF + s * 128 + h0 * 2, s));
            sacc[st] = __builtin_amdgcn_mfma_f32_16x16x32_bf16(kf, qf, sacc[st], 0, 0, 0);
        }
    }

    // ------------- softmax: each lane owns full row t (16 regs) ------------
    float p[4][4];
    float m = -1e30f;
    #pragma unroll
    for (int st = 0; st < 4; ++st)
        #pragma unroll
        for (int r = 0; r < 4; ++r) {
            int s = st * 16 + lg * 4 + r;
            float v = sacc[st][r] * 0.125f;
            v = (s <= t) ? v : -1e30f;       // causal
            p[st][r] = v;
            m = fmaxf(m, v);
        }
    m = fmaxf(m, __shfl_xor(m, 16));
    m = fmaxf(m, __shfl_xor(m, 32));
    float sum = 0.f;
    #pragma unroll
    for (int st = 0; st < 4; ++st)
        #pragma unroll
        for (int r = 0; r < 4; ++r) {
            float e = __expf(p[st][r] - m);
            p[st][r] = e;
            sum += e;
        }
    sum += __shfl_xor(sum, 16);
    sum += __shfl_xor(sum, 32);
    float inv = 1.0f / sum;
    #pragma unroll
    for (int st = 0; st < 4; ++st) {
        bf16x4 pk;
        pk[0] = (bf16_t)(p[st][0] * inv); pk[1] = (bf16_t)(p[st][1] * inv);
        pk[2] = (bf16_t)(p[st][2] * inv); pk[3] = (bf16_t)(p[st][3] * inv);
        *reinterpret_cast<bf16x4*>(qscr + swz(l15 * 128 + (st * 16 + lg * 4) * 2, l15)) = pk;
    }
    // wave-private scratch: same-wave LDS write->read, in-order, no barrier

    // ------------- out = P[16x64] . V[64x64] -------------------------------
    f32x4 oacc[4];
    #pragma unroll
    for (int ht = 0; ht < 4; ++ht) oacc[ht] = (f32x4){0.f, 0.f, 0.f, 0.f};
    #pragma unroll
    for (int ks = 0; ks < 2; ++ks) {
        int s0 = ks * 32 + lg * 8;
        bf16x8 pf = *reinterpret_cast<const bf16x8*>(qscr + swz(l15 * 128 + s0 * 2, l15));
        #pragma unroll
        for (int ht = 0; ht < 4; ++ht) {
            int h = ht * 16 + l15;
            bf16x8 vf = *reinterpret_cast<const bf16x8*>(smem + swz(VT_OFF + h * 128 + s0 * 2, h));
            oacc[ht] = __builtin_amdgcn_mfma_f32_16x16x32_bf16(pf, vf, oacc[ht], 0, 0, 0);
        }
    }

    float* ob = out + (size_t)b * 4096;
    #pragma unroll
    for (int ht = 0; ht < 4; ++ht)
        #pragma unroll
        for (int r = 0; r < 4; ++r)
            ob[(w * 16 + lg * 4 + r) * 64 + ht * 16 + l15] = oacc[ht][r];
}

extern "C" void kernel_launch(void* const* d_in, const int* in_sizes, int n_in,
                              void* d_out, int out_size, void* d_ws, size_t ws_size,
                              hipStream_t stream) {
    const float* x  = (const float*)d_in[0];
    const float* Wq = (const float*)d_in[1];
    const float* Wk = (const float*)d_in[2];
    const float* Wv = (const float*)d_in[3];
    float* out = (float*)d_out;
    int B = in_sizes[0] / (64 * 128);   // 4096
    if (ws_size >= 192 * 128 * sizeof(bf16_t) && d_ws != nullptr) {
        bf16_t* w2 = (bf16_t*)d_ws;
        wcvt_kernel<<<24, 256, 0, stream>>>(Wq, Wk, Wv, w2);
        head_attn_kernel<true><<<B, 256, 0, stream>>>(x, Wq, Wk, Wv, w2, out);
    } else {
        head_attn_kernel<false><<<B, 256, 0, stream>>>(x, Wq, Wk, Wv, nullptr, out);
    }
}